// Round 5
// baseline (231.749 us; speedup 1.0000x reference)
//
#include <hip/hip_runtime.h>
#include <hip/hip_cooperative_groups.h>

namespace cg = cooperative_groups;

typedef __attribute__((ext_vector_type(8))) short bf16x8;   // 8 bf16 = 4 VGPR
typedef __attribute__((ext_vector_type(4))) float f32x4;    // MFMA acc

// Problem constants (fixed by setup_inputs)
#define BB 8
#define TC 1024
#define EE 256
#define KJ 8
#define MSEL 2048
#define V1 17
#define T1 8192
#define TTOT 24576
#define BI_TOT 16384
#define NCOLP 160        // 8 j-groups * 20 (v padded 17->20)
#define WSTRIDE 264      // LDS row stride (bf16) for xs/b1s: 528B -> +4 banks/row, conflict-free
#define GSZ 40960        // packed panel: 160 cols x 256 elems (shorts)

// Packed panel layout: fragment-major. For MFMA fragment (ct=col/16, fe=e>>5),
// lane l=(lq*16+lr) holds elems e=fe*32+lq*8..+7 of col ct*16+lr at
// addr = fid*512 + l*8  (fid = ct*8+fe)  -> B-frag load = base + l*16B, coalesced.
__device__ __forceinline__ int pk_idx(int col, int e) {
    return (((col >> 4) * 8 + (e >> 5)) << 9) + (((e >> 3) & 3) << 7) + ((col & 15) << 3) + (e & 7);
}

// ws layout (bytes): scal ints [0..40] at 0; groups at GRP_OFF; ...
#define GRP_OFF  1024                       // 8*16384 ints
#define WFT_OFF  (GRP_OFF + 524288)         // packed wfT: 40960 shorts = 81920 B
#define B2_OFF   (WFT_OFF + GSZ*2)          // bias2 f32 [160]
#define BF0_OFF  (B2_OFF + 640)             // bf0 f32 [17]
#define WCT_OFF  (BF0_OFF + 128)            // packed wct: 8 x 40960 shorts

__device__ __forceinline__ unsigned short f2bf(float f) {   // RTNE
    union { float f; unsigned u; } x; x.f = f;
    unsigned r = x.u + 0x7fffu + ((x.u >> 16) & 1u);
    return (unsigned short)(r >> 16);
}
__device__ __forceinline__ float bf2f(unsigned short h) {
    union { unsigned u; float f; } x; x.u = ((unsigned)h) << 16;
    return x.f;
}

__device__ __forceinline__ float blockReduceSum256(float v) {
    __shared__ float smr[4];
    #pragma unroll
    for (int d = 32; d; d >>= 1) v += __shfl_down(v, d, 64);
    int lane = threadIdx.x & 63, wid = threadIdx.x >> 6;
    if (lane == 0) smr[wid] = v;
    __syncthreads();
    float r = smr[0] + smr[1] + smr[2] + smr[3];
    __syncthreads();
    return r;
}

// ================= single fused cooperative kernel, grid 512 x 256 =================
// phase1: wfused (0..255) | depth (256..263)
// phase2: wcomb (0..63) | scan (64..71) | bias2 (72..139) | bf0 (140..156)
// phase3: all 512 blocks: grouped MFMA GEMM (g=bid>>6, slot=bid&63, 1 tile each)
__global__ __launch_bounds__(256, 2) void k_all(
        const float* x, const int* value, const int* depth,
        const float* W0, const float* W1, const float* b1, const float* b0,
        const float* Wl, const float* bl,
        int* scal, int* groups, unsigned short* wfT, float* bias2, float* bf0,
        unsigned short* wct, float* out) {
    int bid = blockIdx.x, tid = threadIdx.x;
    __shared__ __align__(16) union SMem {
        struct { float w0s[EE * KJ]; float wls[V1 * 257]; } p1;   // 25.1 KB
        unsigned short b1s[32 * WSTRIDE];                          // 16.9 KB
        unsigned short xs[32 * WSTRIDE];                           // 16.9 KB
    } smu;
    __shared__ int s_red[4];
    __shared__ int s_wt[4], s_lcnt[8], s_lcnt2[8], s_lbase[8];
    __shared__ int obase[32];
    __shared__ unsigned char vflag[32];
    cg::grid_group gg = cg::this_grid();

    // ---------------- phase 1 ----------------
    if (bid < 256) {
        int em = bid;
        for (int idx = tid; idx < EE * KJ; idx += 256) smu.p1.w0s[idx] = W0[em * EE * KJ + idx];
        for (int idx = tid; idx < V1 * EE; idx += 256) {
            int v = idx >> 8, o = idx & 255;
            smu.p1.wls[v * 257 + o] = Wl[idx];
        }
        __syncthreads();
        if (tid < 136) {
            int j = tid / V1, v = tid - j * V1;
            float acc = 0.f;
            #pragma unroll 4
            for (int o = 0; o < EE; ++o) acc += smu.p1.w0s[o * KJ + j] * smu.p1.wls[v * 257 + o];
            wfT[pk_idx(j * 20 + v, em)] = f2bf(acc);
        }
    } else if (bid < 264) {
        int b = bid - 256;
        if (b == 0 && tid < 8) scal[33 + tid] = 0;
        const int4* dp = (const int4*)(depth + b * TTOT);   // 6144 int4
        int m = -2147483648;
        for (int i = tid; i < 6144; i += 256) {
            int4 d = dp[i];
            m = max(max(m, max(d.x, d.y)), max(d.z, d.w));
        }
        #pragma unroll
        for (int dd = 32; dd; dd >>= 1) m = max(m, __shfl_down(m, dd, 64));
        if ((tid & 63) == 0) s_red[tid >> 6] = m;
        __syncthreads();
        int bmax = max(max(s_red[0], s_red[1]), max(s_red[2], s_red[3]));
        if (tid == 0) scal[1 + b] = bmax;
        int c1 = 0, c2 = 0;
        for (int i = tid; i < 6144; i += 256) {
            int4 d = dp[i];
            c1 += (d.x == bmax) + (d.y == bmax) + (d.z == bmax) + (d.w == bmax);
            c2 += (d.x == bmax - 1) + (d.y == bmax - 1) + (d.z == bmax - 1) + (d.w == bmax - 1);
        }
        int cc = (c1 << 16) + c2;           // both <= 24576, block sums fit
        #pragma unroll
        for (int dd = 32; dd; dd >>= 1) cc += __shfl_down(cc, dd, 64);
        __syncthreads();
        if ((tid & 63) == 0) s_red[tid >> 6] = cc;
        __syncthreads();
        if (tid == 0) {
            int tot = s_red[0] + s_red[1] + s_red[2] + s_red[3];
            scal[9 + b] = tot >> 16;           // count of max
            scal[17 + b] = tot & 0xffff;       // count of max-1
        }
    }
    gg.sync();

    // ---------------- phase 2 ----------------
    if (bid < 64) {
        // wcomb: stage W1 slice -> bf16 LDS, MFMA A-frags direct from packed wfT
        int g = bid >> 3;
        int e0 = (bid & 7) * 32;
        {
            int em_l = tid & 63;
            int eb = (tid >> 6) * 8;
            #pragma unroll
            for (int i = 0; i < 8; ++i) {
                int e = eb + i;
                #pragma unroll
                for (int c = 0; c < 4; ++c) {
                    int em = c * 64 + em_l;
                    smu.b1s[e * WSTRIDE + em] = f2bf(W1[(e0 + e) * (EE * KJ) + em * KJ + g]);
                }
            }
        }
        __syncthreads();

        int w = tid >> 6, l = tid & 63;
        int ntile = w & 1, mhalf = w >> 1;
        int lr = l & 15, lq = l >> 4;
        f32x4 acc[5];
        #pragma unroll
        for (int t = 0; t < 5; ++t) acc[t] = (f32x4){0.f, 0.f, 0.f, 0.f};

        #pragma unroll
        for (int ch = 0; ch < 4; ++ch) {
            #pragma unroll
            for (int s = 0; s < 2; ++s) {
                bf16x8 bfr = *(const bf16x8*)&smu.b1s[(ntile * 16 + lr) * WSTRIDE + ch * 64 + s * 32 + lq * 8];
                #pragma unroll
                for (int t = 0; t < 5; ++t) {
                    bf16x8 afr = *(const bf16x8*)&wfT[(((mhalf * 5 + t) * 8 + ch * 2 + s) << 9) + l * 8];
                    acc[t] = __builtin_amdgcn_mfma_f32_16x16x32_bf16(afr, bfr, acc[t], 0, 0, 0);
                }
            }
        }
        #pragma unroll
        for (int t = 0; t < 5; ++t) {
            int ct = mhalf * 5 + t;
            int e = e0 + ntile * 16 + lr;
            #pragma unroll
            for (int r = 0; r < 4; ++r) {
                int col = ct * 16 + lq * 4 + r;
                wct[g * GSZ + pk_idx(col, e)] = f2bf(acc[t][r]);
            }
        }
    } else if (bid < 72) {
        // ---- fused scan + group scatter for batch b ----
        int b = bid - 64;
        int mb = scal[1 + b], cm = scal[9 + b], cm1 = scal[17 + b];
        int gmax = scal[1];
        #pragma unroll
        for (int q = 2; q <= 8; ++q) gmax = max(gmax, scal[q]);
        int len1 = (mb == gmax) ? cm1 : ((mb == gmax - 1) ? cm : 0);
        const int* vb = value + b * TTOT;
        int t0 = tid * 32;
        unsigned mask = 0;
        #pragma unroll
        for (int k = 0; k < 32; k += 4) {
            int4 v = *(const int4*)(vb + t0 + k);
            if (t0 + k + 0 < len1 && v.x == 2) mask |= 1u << (k + 0);
            if (t0 + k + 1 < len1 && v.y == 2) mask |= 1u << (k + 1);
            if (t0 + k + 2 < len1 && v.z == 2) mask |= 1u << (k + 2);
            if (t0 + k + 3 < len1 && v.w == 2) mask |= 1u << (k + 3);
        }
        int cnt = __popc(mask);
        int inc = cnt;
        #pragma unroll
        for (int d = 1; d < 64; d <<= 1) {
            int n = __shfl_up(inc, d, 64);
            if ((tid & 63) >= d) inc += n;
        }
        int lane = tid & 63, wid = tid >> 6;
        if (lane == 63) s_wt[wid] = inc;
        if (tid < 8) { s_lcnt[tid] = 0; s_lcnt2[tid] = 0; }
        __syncthreads();
        int woff = 0;
        for (int w = 0; w < wid; ++w) woff += s_wt[w];
        int off0 = woff + inc - cnt;
        int mix1 = s_wt[0] + s_wt[1] + s_wt[2] + s_wt[3];
        int mix1c = min(mix1, MSEL);
        {   // per-group counts
            int off = off0;
            #pragma unroll
            for (int k = 0; k < 32; ++k) {
                if (mask & (1u << k)) {
                    if (off < MSEL) atomicAdd(&s_lcnt[(t0 + k) & 7], 1);
                    off++;
                }
            }
        }
        if (tid == 0 && mix1c < MSEL) atomicAdd(&s_lcnt[0], MSEL - mix1c);
        __syncthreads();
        if (tid < 8) s_lbase[tid] = atomicAdd(&scal[33 + tid], s_lcnt[tid]);
        __syncthreads();
        {   // scatter
            int off = off0;
            #pragma unroll
            for (int k = 0; k < 32; ++k) {
                if (mask & (1u << k)) {
                    if (off < MSEL) {
                        int t = t0 + k;
                        int g = t & 7;
                        int ls = atomicAdd(&s_lcnt2[g], 1);
                        groups[g * BI_TOT + s_lbase[g] + ls] =
                            ((b * MSEL + off) << 11) | ((t >> 3) << 1) | 1;
                    }
                    off++;
                }
            }
        }
        for (int i = mix1c + tid; i < MSEL; i += 256) {   // invalid (bias-only) rows -> g0
            int ls = atomicAdd(&s_lcnt2[0], 1);
            groups[s_lbase[0] + ls] = (b * MSEL + i) << 11;
        }
    } else if (bid < 140) {
        #pragma unroll
        for (int r = 0; r < 2; ++r) {
            int c17 = (bid - 72) * 2 + r;                 // 0..135
            int j = c17 / V1, v = c17 - j * V1;
            int colP = j * 20 + v;
            float s = blockReduceSum256(b1[tid] * bf2f(wfT[pk_idx(colP, tid)]));
            if (tid == 0) bias2[colP] = s;
        }
    } else if (bid < 157) {
        int v = bid - 140;
        float s = blockReduceSum256(b0[tid] * Wl[v * EE + tid]);
        if (tid == 0) bf0[v] = s + bl[v];
    }
    gg.sync();

    // ---------------- phase 3: grouped MFMA GEMM ----------------
    int g = bid >> 6;
    int slot = bid & 63;
    int cntg = scal[33 + g];
    int row8 = tid >> 3, q8 = tid & 7;
    int w = tid >> 6, l = tid & 63;
    int rw = w & 1, chalf = w >> 1;
    int lr = l & 15, lq = l >> 4;
    const unsigned short* wg = wct + g * GSZ;

    for (int tile = slot; tile * 32 < cntg; tile += 64) {
        int nrows = min(32, cntg - tile * 32);
        __syncthreads();                     // protect xs/meta across tile iterations
        int pk = (row8 < nrows) ? groups[g * BI_TOT + tile * 32 + row8] : 0;
        if (tid < 32) {
            int p2 = (tid < nrows) ? groups[g * BI_TOT + tile * 32 + tid] : 0;
            obase[tid] = (p2 >> 11) * 136;
            vflag[tid] = (tid < nrows) ? (unsigned char)(1 + (p2 & 1)) : (unsigned char)0;
        }
        int bi = pk >> 11;
        int xo = ((bi >> 11) * TC + ((pk >> 1) & 1023)) * EE;
        const float* xp = x + xo;
        float4 xr[8];
        #pragma unroll
        for (int i = 0; i < 8; ++i) xr[i] = *(const float4*)(xp + (q8 + 8 * i) * 4);
        #pragma unroll
        for (int i = 0; i < 8; ++i) {        // commit x tile f32->bf16
            ushort4 pkv;
            pkv.x = f2bf(xr[i].x); pkv.y = f2bf(xr[i].y);
            pkv.z = f2bf(xr[i].z); pkv.w = f2bf(xr[i].w);
            *(ushort4*)&smu.xs[row8 * WSTRIDE + (q8 + 8 * i) * 4] = pkv;
        }
        __syncthreads();                     // xs + meta ready

        f32x4 acc[5];
        #pragma unroll
        for (int t = 0; t < 5; ++t) acc[t] = (f32x4){0.f, 0.f, 0.f, 0.f};
        #pragma unroll
        for (int ch = 0; ch < 4; ++ch) {
            #pragma unroll
            for (int s = 0; s < 2; ++s) {
                bf16x8 afr = *(const bf16x8*)&smu.xs[(rw * 16 + lr) * WSTRIDE + ch * 64 + s * 32 + lq * 8];
                #pragma unroll
                for (int t = 0; t < 5; ++t) {
                    bf16x8 bfr = *(const bf16x8*)&wg[(((chalf * 5 + t) * 8 + ch * 2 + s) << 9) + l * 8];
                    acc[t] = __builtin_amdgcn_mfma_f32_16x16x32_bf16(afr, bfr, acc[t], 0, 0, 0);
                }
            }
        }
        #pragma unroll
        for (int t = 0; t < 5; ++t) {
            int col = (chalf * 5 + t) * 16 + lr;
            int j = col / 20, v = col % 20;
            if (v < V1) {
                float bb = bias2[col] + bf0[v];
                float b0v = bf0[v];
                #pragma unroll
                for (int r = 0; r < 4; ++r) {
                    int row = rw * 16 + lq * 4 + r;
                    int fl = vflag[row];
                    if (fl) out[obase[row] + j * V1 + v] = (fl == 2) ? (acc[t][r] + bb) : b0v;
                }
            }
        }
    }
}

extern "C" void kernel_launch(void* const* d_in, const int* in_sizes, int n_in,
                              void* d_out, int out_size, void* d_ws, size_t ws_size,
                              hipStream_t stream) {
    const float* x     = (const float*)d_in[0];
    const int*   value = (const int*)d_in[1];
    const int*   depth = (const int*)d_in[2];
    // d_in[3] = pos (unused), d_in[4] = num_mix (constant 2048)
    const float* W1    = (const float*)d_in[5];
    const float* b1    = (const float*)d_in[6];
    const float* W0    = (const float*)d_in[7];
    const float* b0    = (const float*)d_in[8];
    const float* Wl    = (const float*)d_in[9];
    const float* bl    = (const float*)d_in[10];
    float* out = (float*)d_out;
    char* ws = (char*)d_ws;

    int*            scal   = (int*)(ws);
    int*            groups = (int*)(ws + GRP_OFF);
    unsigned short* wfT    = (unsigned short*)(ws + WFT_OFF);
    float*          bias2  = (float*)(ws + B2_OFF);
    float*          bf0    = (float*)(ws + BF0_OFF);
    unsigned short* wct    = (unsigned short*)(ws + WCT_OFF);

    void* args[] = {
        (void*)&x, (void*)&value, (void*)&depth,
        (void*)&W0, (void*)&W1, (void*)&b1, (void*)&b0,
        (void*)&Wl, (void*)&bl,
        (void*)&scal, (void*)&groups, (void*)&wfT, (void*)&bias2, (void*)&bf0,
        (void*)&wct, (void*)&out
    };
    hipLaunchCooperativeKernel((const void*)k_all, dim3(512), dim3(256),
                               args, 0, stream);
}

// Round 6
// 114.655 us; speedup vs baseline: 2.0213x; 2.0213x over previous
//
#include <hip/hip_runtime.h>

typedef __attribute__((ext_vector_type(8))) short bf16x8;   // 8 bf16 = 4 VGPR
typedef __attribute__((ext_vector_type(4))) float f32x4;    // MFMA acc

// Problem constants (fixed by setup_inputs)
#define BB 8
#define TC 1024
#define EE 256
#define KJ 8
#define MSEL 2048
#define V1 17
#define T1 8192
#define TTOT 24576
#define BI_TOT 16384
#define NCOLP 160        // 8 j-groups * 20 (v padded 17->20)
#define WSTRIDE 264      // K-dim stride in bf16 elems (16B-aligned rows, bank-staggered)

// scal layout (ints): [0]=globalmax [1..8]=max_b [9..16]=cnt(max)_b [17..24]=cnt(max-1)_b [33..40]=grpcnt
#define SCAL_OFF 0
#define GRP_OFF  1024                       // 8*16384 ints
#define WFT_OFF  (GRP_OFF + 524288)         // wfT bf16 [160][264]
#define B2_OFF   (WFT_OFF + NCOLP*WSTRIDE*2)// bias2 f32 [160]
#define BF0_OFF  (B2_OFF + 640)             // bf0 f32 [17]
#define WCT_OFF  (BF0_OFF + 128)            // wct bf16 [8][160][264]

__device__ __forceinline__ unsigned short f2bf(float f) {   // RTNE
    union { float f; unsigned u; } x; x.f = f;
    unsigned r = x.u + 0x7fffu + ((x.u >> 16) & 1u);
    return (unsigned short)(r >> 16);
}
__device__ __forceinline__ float bf2f(unsigned short h) {
    union { unsigned u; float f; } x; x.u = ((unsigned)h) << 16;
    return x.f;
}

__device__ __forceinline__ float blockReduceSum256(float v) {
    __shared__ float sm[4];
    #pragma unroll
    for (int d = 32; d; d >>= 1) v += __shfl_down(v, d, 64);
    int lane = threadIdx.x & 63, wid = threadIdx.x >> 6;
    if (lane == 0) sm[wid] = v;
    __syncthreads();
    float r = sm[0] + sm[1] + sm[2] + sm[3];
    __syncthreads();
    return r;
}

// ============ Dispatch 1: wfused (blocks 0..255) | depth stats (blocks 256..263) ============
__global__ __launch_bounds__(256) void k_pre(const float* W0, const float* Wl, const int* depth,
                                             unsigned short* wfT, int* scal) {
    int bid = blockIdx.x, tid = threadIdx.x;
    __shared__ float w0s[EE * KJ];
    __shared__ float wls[V1 * 257];
    __shared__ int s_red[4];
    if (bid < 256) {
        int em = bid;
        for (int idx = tid; idx < EE * KJ; idx += 256) w0s[idx] = W0[em * EE * KJ + idx];
        for (int idx = tid; idx < V1 * EE; idx += 256) {
            int v = idx >> 8, o = idx & 255;
            wls[v * 257 + o] = Wl[idx];
        }
        __syncthreads();
        if (tid < 136) {
            int j = tid / V1, v = tid - j * V1;
            float acc = 0.f;
            #pragma unroll 4
            for (int o = 0; o < EE; ++o) acc += w0s[o * KJ + j] * wls[v * 257 + o];
            wfT[(j * 20 + v) * WSTRIDE + em] = f2bf(acc);
        }
    } else {
        int b = bid - 256;
        if (b == 0 && tid < 8) scal[33 + tid] = 0;
        const int4* dp = (const int4*)(depth + b * TTOT);   // 6144 int4
        int m = -2147483648;
        for (int i = tid; i < 6144; i += 256) {
            int4 d = dp[i];
            m = max(max(m, max(d.x, d.y)), max(d.z, d.w));
        }
        #pragma unroll
        for (int dd = 32; dd; dd >>= 1) m = max(m, __shfl_down(m, dd, 64));
        if ((tid & 63) == 0) s_red[tid >> 6] = m;
        __syncthreads();
        int bmax = max(max(s_red[0], s_red[1]), max(s_red[2], s_red[3]));
        if (tid == 0) { atomicMax(&scal[0], bmax); scal[1 + b] = bmax; }
        int c1 = 0, c2 = 0;
        for (int i = tid; i < 6144; i += 256) {
            int4 d = dp[i];
            c1 += (d.x == bmax) + (d.y == bmax) + (d.z == bmax) + (d.w == bmax);
            c2 += (d.x == bmax - 1) + (d.y == bmax - 1) + (d.z == bmax - 1) + (d.w == bmax - 1);
        }
        int cc = (c1 << 16) + c2;           // both <= 24576, block sums fit
        #pragma unroll
        for (int dd = 32; dd; dd >>= 1) cc += __shfl_down(cc, dd, 64);
        __syncthreads();
        if ((tid & 63) == 0) s_red[tid >> 6] = cc;
        __syncthreads();
        if (tid == 0) {
            int tot = s_red[0] + s_red[1] + s_red[2] + s_red[3];
            scal[9 + b] = tot >> 16;           // count of max
            scal[17 + b] = tot & 0xffff;       // count of max-1
        }
    }
}

// ============ Dispatch 2: wcomb MFMA (0..63) | scan+group (64..71) | bf0 (72..88) | bias2 (89..156) ============
__global__ __launch_bounds__(256) void k_mid(
        const int* value, const float* W1, const float* b1, const float* b0,
        const float* Wl, const float* bl,
        int* scal, int* groups, const unsigned short* wfT, float* bias2, float* bf0,
        unsigned short* wct) {
    int bid = blockIdx.x, tid = threadIdx.x;
    __shared__ union {
        struct { unsigned short b1s[32 * WSTRIDE]; unsigned short af[NCOLP * 72]; } w;
    } sm;
    __shared__ int s_wt[4], s_lcnt[8], s_lcnt2[8], s_lbase[8];
    if (bid < 64) {
        int g = bid >> 3;
        int e0 = (bid & 7) * 32;
        unsigned short* b1s = sm.w.b1s;
        unsigned short* af = sm.w.af;
        {   // stage B: W1 slice -> bf16, lanes consecutive in em
            int em_l = tid & 63;
            int eb = (tid >> 6) * 8;
            #pragma unroll
            for (int i = 0; i < 8; ++i) {
                int e = eb + i;
                #pragma unroll
                for (int c = 0; c < 4; ++c) {
                    int em = c * 64 + em_l;
                    b1s[e * WSTRIDE + em] = f2bf(W1[(e0 + e) * (EE * KJ) + em * KJ + g]);
                }
            }
        }
        for (int idx = tid; idx < 1280; idx += 256) {   // stage A chunk 0
            int row = idx >> 3, f = idx & 7;
            ((int4*)af)[row * 9 + f] = ((const int4*)wfT)[row * 33 + f];
        }
        __syncthreads();

        int w = tid >> 6, l = tid & 63;
        int ntile = w & 1, mhalf = w >> 1;
        int lr = l & 15, lq = l >> 4;
        f32x4 acc[5];
        #pragma unroll
        for (int t = 0; t < 5; ++t) acc[t] = (f32x4){0.f, 0.f, 0.f, 0.f};

        for (int ch = 0; ch < 4; ++ch) {
            if (ch) {
                __syncthreads();
                for (int idx = tid; idx < 1280; idx += 256) {
                    int row = idx >> 3, f = idx & 7;
                    ((int4*)af)[row * 9 + f] = ((const int4*)wfT)[row * 33 + ch * 8 + f];
                }
                __syncthreads();
            }
            #pragma unroll
            for (int s = 0; s < 2; ++s) {
                bf16x8 bfr = *(const bf16x8*)&b1s[(ntile * 16 + lr) * WSTRIDE + ch * 64 + s * 32 + lq * 8];
                #pragma unroll
                for (int t = 0; t < 5; ++t) {
                    bf16x8 afr = *(const bf16x8*)&af[((mhalf * 5 + t) * 16 + lr) * 72 + s * 32 + lq * 8];
                    acc[t] = __builtin_amdgcn_mfma_f32_16x16x32_bf16(afr, bfr, acc[t], 0, 0, 0);
                }
            }
        }
        #pragma unroll
        for (int t = 0; t < 5; ++t) {
            int m = (mhalf * 5 + t) * 16 + lq * 4;
            int n = e0 + ntile * 16 + lr;
            #pragma unroll
            for (int r = 0; r < 4; ++r)
                wct[(g * NCOLP + m + r) * WSTRIDE + n] = f2bf(acc[t][r]);
        }
    } else if (bid < 72) {
        // ---- fused scan + group scatter for batch b ----
        int b = bid - 64;
        int gmax = scal[0];
        int mb = scal[1 + b], cm = scal[9 + b], cm1 = scal[17 + b];
        int len1 = (mb == gmax) ? cm1 : ((mb == gmax - 1) ? cm : 0);
        const int* vb = value + b * TTOT;
        int t0 = tid * 32;
        unsigned mask = 0;
        #pragma unroll
        for (int k = 0; k < 32; k += 4) {
            int4 v = *(const int4*)(vb + t0 + k);
            if (t0 + k + 0 < len1 && v.x == 2) mask |= 1u << (k + 0);
            if (t0 + k + 1 < len1 && v.y == 2) mask |= 1u << (k + 1);
            if (t0 + k + 2 < len1 && v.z == 2) mask |= 1u << (k + 2);
            if (t0 + k + 3 < len1 && v.w == 2) mask |= 1u << (k + 3);
        }
        int cnt = __popc(mask);
        int inc = cnt;
        #pragma unroll
        for (int d = 1; d < 64; d <<= 1) {
            int n = __shfl_up(inc, d, 64);
            if ((tid & 63) >= d) inc += n;
        }
        int lane = tid & 63, wid = tid >> 6;
        if (lane == 63) s_wt[wid] = inc;
        if (tid < 8) { s_lcnt[tid] = 0; s_lcnt2[tid] = 0; }
        __syncthreads();
        int woff = 0;
        for (int w = 0; w < wid; ++w) woff += s_wt[w];
        int off0 = woff + inc - cnt;
        int mix1 = s_wt[0] + s_wt[1] + s_wt[2] + s_wt[3];
        int mix1c = min(mix1, MSEL);
        {   // phase A: per-group counts
            int off = off0;
            #pragma unroll
            for (int k = 0; k < 32; ++k) {
                if (mask & (1u << k)) {
                    if (off < MSEL) atomicAdd(&s_lcnt[(t0 + k) & 7], 1);
                    off++;
                }
            }
        }
        if (tid == 0 && mix1c < MSEL) atomicAdd(&s_lcnt[0], MSEL - mix1c);
        __syncthreads();
        if (tid < 8) s_lbase[tid] = atomicAdd(&scal[33 + tid], s_lcnt[tid]);
        __syncthreads();
        {   // phase B: scatter
            int off = off0;
            #pragma unroll
            for (int k = 0; k < 32; ++k) {
                if (mask & (1u << k)) {
                    if (off < MSEL) {
                        int t = t0 + k;
                        int g = t & 7;
                        int ls = atomicAdd(&s_lcnt2[g], 1);
                        groups[g * BI_TOT + s_lbase[g] + ls] =
                            ((b * MSEL + off) << 11) | ((t >> 3) << 1) | 1;
                    }
                    off++;
                }
            }
        }
        for (int i = mix1c + tid; i < MSEL; i += 256) {   // invalid (bias-only) rows -> g0
            int ls = atomicAdd(&s_lcnt2[0], 1);
            groups[s_lbase[0] + ls] = (b * MSEL + i) << 11;
        }
    } else if (bid < 89) {
        int v = bid - 72;
        float s = blockReduceSum256(b0[tid] * Wl[v * EE + tid]);
        if (tid == 0) bf0[v] = s + bl[v];
    } else {
        #pragma unroll
        for (int r = 0; r < 2; ++r) {
            int c17 = (bid - 89) * 2 + r;                 // 0..135
            int j = c17 / V1, v = c17 - j * V1;
            int colP = j * 20 + v;
            float s = blockReduceSum256(b1[tid] * bf2f(wfT[colP * WSTRIDE + tid]));
            if (tid == 0) bias2[colP] = s;
        }
    }
}

// ============ Dispatch 3: main grouped MFMA GEMM ============
// grid 1024 = 8 groups x 128 tile slots; block loops tiles by +128 (skew-safe)
__global__ __launch_bounds__(256) void k_main(const float* x, const unsigned short* wct,
        const int* scal, const int* groups, const float* bias2, const float* bf0, float* out) {
    int g = blockIdx.x >> 7;
    int tile0 = blockIdx.x & 127;
    int cntg = scal[33 + g];

    __shared__ __align__(16) unsigned short xs[32 * WSTRIDE];    // [row][e] bf16
    __shared__ __align__(16) unsigned short wts[NCOLP * 72];     // [col][e-chunk(64)+pad]
    __shared__ int xoffs[32], obase[32];
    __shared__ unsigned char vflag[32];
    int tid = threadIdx.x;
    const int4* wsrc = (const int4*)wct;

    for (int tile = tile0; tile * 32 < cntg; tile += 128) {
        int nrows = min(32, cntg - tile * 32);
        __syncthreads();                      // protect LDS reuse across tile iterations
        if (tid < 32) {
            int flag = 0, xo = 0, ob = 0;
            if (tid < nrows) {
                int p = groups[g * BI_TOT + tile * 32 + tid];
                int valid = p & 1;
                int tq = (p >> 1) & 1023;
                int bi = p >> 11;
                int b = bi >> 11;
                xo = (b * TC + tq) * EE;
                ob = bi * 136;
                flag = 1 + valid;
            }
            xoffs[tid] = xo; obase[tid] = ob; vflag[tid] = (unsigned char)flag;
        }
        __syncthreads();
        {   // stage x rows f32->bf16: row = tid>>3, 8 float4 each
            int row = tid >> 3, q = tid & 7;
            const float* xp = x + xoffs[row];
            #pragma unroll
            for (int i = 0; i < 8; ++i) {
                int f4 = q + 8 * i;
                float4 v = *(const float4*)(xp + f4 * 4);
                ushort4 pk;
                pk.x = f2bf(v.x); pk.y = f2bf(v.y); pk.z = f2bf(v.z); pk.w = f2bf(v.w);
                *(ushort4*)&xs[row * WSTRIDE + f4 * 4] = pk;
            }
        }
        for (int idx = tid; idx < 1280; idx += 256) {    // stage W chunk 0
            int row = idx >> 3, f = idx & 7;
            ((int4*)wts)[row * 9 + f] = wsrc[(g * NCOLP + row) * 33 + f];
        }
        __syncthreads();

        int w = tid >> 6, l = tid & 63;
        int rw = w & 1, chalf = w >> 1;
        int lr = l & 15, lq = l >> 4;
        f32x4 acc[5];
        #pragma unroll
        for (int t = 0; t < 5; ++t) acc[t] = (f32x4){0.f, 0.f, 0.f, 0.f};

        for (int ch = 0; ch < 4; ++ch) {
            if (ch) {
                __syncthreads();
                for (int idx = tid; idx < 1280; idx += 256) {
                    int row = idx >> 3, f = idx & 7;
                    ((int4*)wts)[row * 9 + f] = wsrc[(g * NCOLP + row) * 33 + ch * 8 + f];
                }
                __syncthreads();
            }
            #pragma unroll
            for (int s = 0; s < 2; ++s) {
                bf16x8 afr = *(const bf16x8*)&xs[(rw * 16 + lr) * WSTRIDE + ch * 64 + s * 32 + lq * 8];
                #pragma unroll
                for (int t = 0; t < 5; ++t) {
                    bf16x8 bfr = *(const bf16x8*)&wts[((chalf * 5 + t) * 16 + lr) * 72 + s * 32 + lq * 8];
                    acc[t] = __builtin_amdgcn_mfma_f32_16x16x32_bf16(afr, bfr, acc[t], 0, 0, 0);
                }
            }
        }
        #pragma unroll
        for (int t = 0; t < 5; ++t) {
            int col = (chalf * 5 + t) * 16 + lr;
            int j = col / 20, v = col % 20;
            if (v < V1) {
                float bb = bias2[col] + bf0[v];
                float b0v = bf0[v];
                #pragma unroll
                for (int r = 0; r < 4; ++r) {
                    int row = rw * 16 + lq * 4 + r;
                    int fl = vflag[row];
                    if (fl) out[obase[row] + j * V1 + v] = (fl == 2) ? (acc[t][r] + bb) : b0v;
                }
            }
        }
    }
}

extern "C" void kernel_launch(void* const* d_in, const int* in_sizes, int n_in,
                              void* d_out, int out_size, void* d_ws, size_t ws_size,
                              hipStream_t stream) {
    const float* x     = (const float*)d_in[0];
    const int*   value = (const int*)d_in[1];
    const int*   depth = (const int*)d_in[2];
    // d_in[3] = pos (unused), d_in[4] = num_mix (constant 2048)
    const float* W1    = (const float*)d_in[5];
    const float* b1    = (const float*)d_in[6];
    const float* W0    = (const float*)d_in[7];
    const float* b0    = (const float*)d_in[8];
    const float* Wl    = (const float*)d_in[9];
    const float* bl    = (const float*)d_in[10];
    float* out = (float*)d_out;
    char* ws = (char*)d_ws;

    int*            scal   = (int*)(ws + SCAL_OFF);
    int*            groups = (int*)(ws + GRP_OFF);
    unsigned short* wfT    = (unsigned short*)(ws + WFT_OFF);
    float*          bias2  = (float*)(ws + B2_OFF);
    float*          bf0    = (float*)(ws + BF0_OFF);
    unsigned short* wct    = (unsigned short*)(ws + WCT_OFF);

    k_pre <<<dim3(264),  dim3(256), 0, stream>>>(W0, Wl, depth, wfT, scal);
    k_mid <<<dim3(157),  dim3(256), 0, stream>>>(value, W1, b1, b0, Wl, bl,
                                                 scal, groups, wfT, bias2, bf0, wct);
    k_main<<<dim3(1024), dim3(256), 0, stream>>>(x, wct, scal, groups, bias2, bf0, out);
}